// Round 1
// baseline (174.609 us; speedup 1.0000x reference)
//
#include <hip/hip_runtime.h>
#include <hip/hip_bf16.h>
#include <stdint.h>

// Problem dims (fixed by the reference)
constexpr int T_TOK = 8192;
constexpr int D_DIM = 1024;
constexpr int H_DIM = 2048;
constexpr int E_NUM = 8;

typedef __bf16 bf16x8 __attribute__((ext_vector_type(8)));
typedef float  f32x4  __attribute__((ext_vector_type(4)));

__device__ __forceinline__ unsigned short f2bf(float f) {
  union { float f; unsigned u; } a; a.f = f;
  unsigned r = a.u + 0x7fffu + ((a.u >> 16) & 1u);   // RNE
  return (unsigned short)(r >> 16);
}
__device__ __forceinline__ float bf2f(unsigned short h) {
  union { unsigned u; float f; } a; a.u = ((unsigned)h) << 16;
  return a.f;
}

// ---------------- fp32 -> bf16 conversion (vectorized) ----------------
__global__ void cvt_f32_bf16(const float* __restrict__ src,
                             unsigned short* __restrict__ dst, int n4) {
  int i = blockIdx.x * blockDim.x + threadIdx.x;
  int stride = gridDim.x * blockDim.x;
  for (; i < n4; i += stride) {
    float4 v = reinterpret_cast<const float4*>(src)[i];
    ushort4 o;
    o.x = f2bf(v.x); o.y = f2bf(v.y); o.z = f2bf(v.z); o.w = f2bf(v.w);
    reinterpret_cast<ushort4*>(dst)[i] = o;
  }
}

// ---------------- grouped GEMM, m97-style 128x128 tile ----------------
// A: (T, K) bf16 row-major. B: (E, N, K) bf16 row-major (i.e. C = A @ B^T).
// RELU2: C = bf16(bf16(relu(acc))^2) stored bf16; else C = float(bf16(acc)).
template <int K_DIM, int N_DIM, bool RELU2>
__global__ __launch_bounds__(256, 2)
void grouped_gemm_bt(const unsigned short* __restrict__ A,
                     const unsigned short* __restrict__ B,
                     const int* __restrict__ counts,
                     void* __restrict__ Cout) {
  const int tid  = threadIdx.x;
  const int wid  = tid >> 6;
  const int lane = tid & 63;

  // ---- map blockIdx.x -> (expert, local row tile) from device-side counts
  int t = blockIdx.x;
  int e = -1, rowBase = 0, rowsValid = 0;
  {
    int tiles = 0, acc = 0;
#pragma unroll
    for (int i = 0; i < E_NUM; ++i) {
      int n  = counts[i];
      int nt = (n + 127) >> 7;
      if (e < 0 && t < tiles + nt) {
        e = i;
        int lt = t - tiles;
        rowBase   = acc + lt * 128;
        rowsValid = n - lt * 128;
        if (rowsValid > 128) rowsValid = 128;
      }
      tiles += nt; acc += n;
    }
  }
  if (e < 0) return;

  const int colBase = blockIdx.y * 128;

  __shared__ char ldsA[128 * 64];   // [row][32 bf16] rows of 64B
  __shared__ char ldsB[128 * 64];

  const char* gA = (const char*)A + (size_t)rowBase * (K_DIM * 2);
  const char* gB = (const char*)B + ((size_t)e * N_DIM + colBase) * (size_t)(K_DIM * 2);

  const int sRow = tid >> 2;            // staging row for issue 0 (0..63)
  const int sCb  = (tid & 3) * 16;      // byte offset within row (0/16/32/48)

  const int wr = wid >> 1, wc = wid & 1;
  const int aFragBase = (wr * 64 + (lane & 15)) * 64 + (lane >> 4) * 16;
  const int bFragBase = (wc * 64 + (lane & 15)) * 64 + (lane >> 4) * 16;

  f32x4 acc[4][4];
  const f32x4 zero = {0.f, 0.f, 0.f, 0.f};
#pragma unroll
  for (int m = 0; m < 4; ++m)
#pragma unroll
    for (int n = 0; n < 4; ++n) acc[m][n] = zero;

  for (int k0 = 0; k0 < K_DIM; k0 += 32) {
#pragma unroll
    for (int i = 0; i < 2; ++i) {
      int r  = sRow + i * 64;
      int rA = (r < rowsValid) ? r : (rowsValid - 1);   // clamp ragged M rows
      const char* srcA = gA + (size_t)rA * (K_DIM * 2) + k0 * 2 + sCb;
      __builtin_amdgcn_global_load_lds(
          (const __attribute__((address_space(1))) void*)srcA,
          (__attribute__((address_space(3))) void*)(ldsA + i * 4096 + wid * 1024),
          16, 0, 0);
      const char* srcB = gB + (size_t)r * (K_DIM * 2) + k0 * 2 + sCb;
      __builtin_amdgcn_global_load_lds(
          (const __attribute__((address_space(1))) void*)srcB,
          (__attribute__((address_space(3))) void*)(ldsB + i * 4096 + wid * 1024),
          16, 0, 0);
    }
    __syncthreads();   // drains vmcnt before barrier (compiler-inserted)

    bf16x8 aF[4], bF[4];
#pragma unroll
    for (int m = 0; m < 4; ++m)
      aF[m] = *reinterpret_cast<const bf16x8*>(ldsA + aFragBase + m * 16 * 64);
#pragma unroll
    for (int n = 0; n < 4; ++n)
      bF[n] = *reinterpret_cast<const bf16x8*>(ldsB + bFragBase + n * 16 * 64);

#pragma unroll
    for (int m = 0; m < 4; ++m)
#pragma unroll
      for (int n = 0; n < 4; ++n)
        acc[m][n] = __builtin_amdgcn_mfma_f32_16x16x32_bf16(aF[m], bF[n], acc[m][n], 0, 0, 0);

    __syncthreads();
  }

  // ---- epilogue. C/D layout: col = lane&15, row = (lane>>4)*4 + j
  const int rBase = wr * 64 + (lane >> 4) * 4;
  const int cCol0 = colBase + wc * 64 + (lane & 15);
#pragma unroll
  for (int m = 0; m < 4; ++m) {
#pragma unroll
    for (int n = 0; n < 4; ++n) {
#pragma unroll
      for (int j = 0; j < 4; ++j) {
        int r = rBase + m * 16 + j;
        if (r < rowsValid) {
          size_t idx = (size_t)(rowBase + r) * N_DIM + (cCol0 + n * 16);
          float v = acc[m][n][j];
          if (RELU2) {
            v = v > 0.f ? v : 0.f;
            float hb = bf2f(f2bf(v));            // bf16(relu(acc))
            ((unsigned short*)Cout)[idx] = f2bf(hb * hb);  // bf16 square
          } else {
            ((float*)Cout)[idx] = bf2f(f2bf(v)); // float(bf16(acc))
          }
        }
      }
    }
  }
}

extern "C" void kernel_launch(void* const* d_in, const int* in_sizes, int n_in,
                              void* d_out, int out_size, void* d_ws, size_t ws_size,
                              hipStream_t stream) {
  const float* x   = (const float*)d_in[0];
  const int*   cnt = (const int*)d_in[1];
  const float* wu  = (const float*)d_in[2];
  const float* wd  = (const float*)d_in[3];
  float* out = (float*)d_out;
  char*  ws  = (char*)d_ws;

  unsigned short* xb  = (unsigned short*)(ws);                    // 16 MiB
  unsigned short* wub = (unsigned short*)(ws + (16u << 20));      // 32 MiB
  unsigned short* wdb = (unsigned short*)(ws + (48u << 20));      // 32 MiB
  unsigned short* hbuf= (unsigned short*)(ws + (80u << 20));      // 32 MiB

  cvt_f32_bf16<<<2048, 256, 0, stream>>>(x,  xb,  T_TOK * D_DIM / 4);
  cvt_f32_bf16<<<2048, 256, 0, stream>>>(wu, wub, E_NUM * H_DIM * D_DIM / 4);
  cvt_f32_bf16<<<2048, 256, 0, stream>>>(wd, wdb, E_NUM * D_DIM * H_DIM / 4);

  // max row tiles = floor(T/128) + E = 72 (blocks past the real count exit)
  grouped_gemm_bt<D_DIM, H_DIM, true ><<<dim3(72, H_DIM / 128), 256, 0, stream>>>(
      xb, wub, cnt, (void*)hbuf);
  grouped_gemm_bt<H_DIM, D_DIM, false><<<dim3(72, D_DIM / 128), 256, 0, stream>>>(
      hbuf, wdb, cnt, (void*)out);
}

// Round 2
// 129.207 us; speedup vs baseline: 1.3514x; 1.3514x over previous
//
#include <hip/hip_runtime.h>
#include <stdint.h>

constexpr int T_TOK = 8192;
constexpr int D_DIM = 1024;
constexpr int H_DIM = 2048;
constexpr int E_NUM = 8;

typedef __bf16 bf16x8 __attribute__((ext_vector_type(8)));
typedef float  f32x4  __attribute__((ext_vector_type(4)));

static __device__ __forceinline__ unsigned short f2bf(float f) {
  union { float f; unsigned u; } a; a.f = f;
  unsigned r = a.u + 0x7fffu + ((a.u >> 16) & 1u);   // RNE
  return (unsigned short)(r >> 16);
}
static __device__ __forceinline__ float bf2f(unsigned short h) {
  union { unsigned u; float f; } a; a.u = ((unsigned)h) << 16;
  return a.f;
}

// ---------------- fp32 -> bf16 conversion (vectorized) ----------------
__global__ void cvt_f32_bf16(const float* __restrict__ src,
                             unsigned short* __restrict__ dst, int n4) {
  int i = blockIdx.x * blockDim.x + threadIdx.x;
  int stride = gridDim.x * blockDim.x;
  for (; i < n4; i += stride) {
    float4 v = reinterpret_cast<const float4*>(src)[i];
    ushort4 o;
    o.x = f2bf(v.x); o.y = f2bf(v.y); o.z = f2bf(v.z); o.w = f2bf(v.w);
    reinterpret_cast<ushort4*>(dst)[i] = o;
  }
}

// ------------- 8-phase 256-wide grouped GEMM (HK-style schedule) -------------
// A: (T,K) bf16 rm. B: (E,N,K) bf16 rm. C = A @ B[e]^T per segment.
// Half-tiles are STRIPED row sets so each phase's staging only overwrites
// regions last ds_read >=1 barrier earlier. Counted vmcnt at phases 4/8 only.

#define FENCE() asm volatile("" ::: "memory")
#define BARRIER() do { FENCE(); __builtin_amdgcn_s_barrier(); FENCE(); } while (0)
#define WAIT_LGKM0() asm volatile("s_waitcnt lgkmcnt(0)" ::: "memory")
#define WAIT_VM(N) asm volatile("s_waitcnt vmcnt(%0)" :: "i"(N) : "memory")

template <int K_DIM, int N_DIM, int BN, bool RELU2>
__global__ __launch_bounds__(512, 2)
void gg8(const unsigned short* __restrict__ A,
         const unsigned short* __restrict__ Bw,
         const int* __restrict__ counts,
         void* __restrict__ Cout) {
  constexpr int BM = 256, BK = 64;
  constexpr int NT = K_DIM / BK;      // K-tiles
  constexpr int NITER = NT / 2;       // 2 K-tiles per iteration
  constexpr int WNC = BN / 4;         // per-wave output cols (64 or 32)
  constexpr int NACC = WNC / 16;      // acc cols (4 or 2)
  constexpr int NQN = NACC / 2;       // B frags per quadrant (2 or 1)
  constexpr int BLOADS = (BN == 256) ? 2 : 1;  // per-thread loads per B half
  constexpr int VN = 4 + BLOADS;      // counted vmcnt (3 half-tiles in flight)

  const int tid  = threadIdx.x;
  const int wid  = tid >> 6;
  const int lane = tid & 63;
  const int wr   = wid >> 2;   // 0..1
  const int wc   = wid & 3;    // 0..3

  // ---- map blockIdx.x -> (expert, 256-row tile)
  int t = blockIdx.x;
  int e = -1, rowBase = 0, rowsValid = 0;
  {
    int tiles = 0, off = 0;
#pragma unroll
    for (int i = 0; i < E_NUM; ++i) {
      int n  = counts[i];
      int nt = (n + BM - 1) / BM;
      if (e < 0 && t < tiles + nt) {
        e = i;
        int lt = t - tiles;
        rowBase   = off + lt * BM;
        rowsValid = n - lt * BM;
        if (rowsValid > BM) rowsValid = BM;
      }
      tiles += nt; off += n;
    }
  }
  if (e < 0) return;
  const int colBase = blockIdx.y * BN;

  __shared__ __align__(1024) char lds[(BM + BN) * BK * 2 * 2];  // 128/96 KiB
  auto ldsA = [&](int b) -> char* { return lds + b * (BM * 128); };
  auto ldsB = [&](int b) -> char* { return lds + 2 * (BM * 128) + b * (BN * 128); };

  const char* gA = (const char*)A + (size_t)rowBase * (K_DIM * 2);
  const char* gB = (const char*)(Bw + ((size_t)e * N_DIM + colBase) * K_DIM);

  const int lr8 = lane >> 3;        // 0..7 : row within 8-row block
  const int gsw = (lane & 7) ^ lr8; // inverse-swizzled source granule

  // stage one A half-tile (128 striped rows, 2 gload_lds/wave)
  auto stageA = [&](int buf, int alpha, int kt) {
#pragma unroll
    for (int j = 0; j < 2; ++j) {
      int bi   = j * 8 + wid;                                    // 0..15
      int row0 = (bi >> 3) * 128 + alpha * 64 + (bi & 7) * 8;
      int sr   = row0 + lr8;
      if (sr >= rowsValid) sr = rowsValid - 1;                   // ragged clamp
      const char* src = gA + (size_t)sr * (K_DIM * 2) + (size_t)kt * 128 + gsw * 16;
      __builtin_amdgcn_global_load_lds(
          (const __attribute__((address_space(1))) void*)src,
          (__attribute__((address_space(3))) void*)(ldsA(buf) + row0 * 128),
          16, 0, 0);
    }
  };
  // stage one B half-tile (BN/2 striped rows)
  auto stageB = [&](int buf, int alpha, int kt) {
#pragma unroll
    for (int j = 0; j < BLOADS; ++j) {
      int bi   = j * 8 + wid;
      int row0 = (BN == 256) ? ((bi >> 2) * 64 + alpha * 32 + (bi & 3) * 8)
                             : ((bi >> 1) * 32 + alpha * 16 + (bi & 1) * 8);
      int sr   = row0 + lr8;
      const char* src = gB + (size_t)sr * (K_DIM * 2) + (size_t)kt * 128 + gsw * 16;
      __builtin_amdgcn_global_load_lds(
          (const __attribute__((address_space(1))) void*)src,
          (__attribute__((address_space(3))) void*)(ldsB(buf) + row0 * 128),
          16, 0, 0);
    }
  };

  const int rowLane = lane & 15;
  const int grpA    = lane >> 4;    // 0..3
  const int swzm    = lane & 7;

  bf16x8 aF[4][2];
  bf16x8 bF[2][NQN][2];
  f32x4  accC[8][NACC];
#pragma unroll
  for (int m = 0; m < 8; ++m)
#pragma unroll
    for (int n = 0; n < NACC; ++n) accC[m][n] = (f32x4){0.f, 0.f, 0.f, 0.f};

  auto readA = [&](int buf, int rh) {
    const char* base = ldsA(buf) + (wr * 128 + rh * 64 + rowLane) * 128;
#pragma unroll
    for (int m = 0; m < 4; ++m)
#pragma unroll
      for (int ks = 0; ks < 2; ++ks) {
        int g = (ks * 4 + grpA) ^ swzm;                 // swizzled read
        aF[m][ks] = *(const bf16x8*)(base + m * (16 * 128) + g * 16);
      }
  };
  auto readB = [&](int buf, int ch, bf16x8 (&dst)[NQN][2]) {
    const char* base = ldsB(buf) + (wc * WNC + ch * (WNC / 2) + rowLane) * 128;
#pragma unroll
    for (int n = 0; n < NQN; ++n)
#pragma unroll
      for (int ks = 0; ks < 2; ++ks) {
        int g = (ks * 4 + grpA) ^ swzm;
        dst[n][ks] = *(const bf16x8*)(base + n * (16 * 128) + g * 16);
      }
  };

#define MFMAQ(RH, BFA)                                                        \
  do {                                                                        \
    __builtin_amdgcn_s_setprio(1);                                            \
    _Pragma("unroll")                                                         \
    for (int m_ = 0; m_ < 4; ++m_) {                                          \
      _Pragma("unroll")                                                       \
      for (int n_ = 0; n_ < NQN; ++n_) {                                      \
        f32x4 c_ = accC[(RH) * 4 + m_][(CHIDX) * NQN + n_];                   \
        c_ = __builtin_amdgcn_mfma_f32_16x16x32_bf16(aF[m_][0], BFA[n_][0], c_, 0, 0, 0); \
        c_ = __builtin_amdgcn_mfma_f32_16x16x32_bf16(aF[m_][1], BFA[n_][1], c_, 0, 0, 0); \
        accC[(RH) * 4 + m_][(CHIDX) * NQN + n_] = c_;                         \
      }                                                                       \
    }                                                                         \
    __builtin_amdgcn_s_setprio(0);                                            \
  } while (0)

  // ---- prologue: tile0 {A0,B0,A1,B1} + tile1 {A0,B0,A1}; B1(tile1) at P1.
  stageA(0, 0, 0); stageB(0, 0, 0); stageA(0, 1, 0); stageB(0, 1, 0);
  stageA(1, 0, 1); stageB(1, 0, 1); stageA(1, 1, 1);
  WAIT_VM(VN);
  BARRIER();

  for (int it = 0; it < NITER; ++it) {
    const int t0  = 2 * it;
    const int kB1 = t0 + 1;
    const int kN0 = (t0 + 2 < NT) ? t0 + 2 : NT - 1;   // clamped (tail garbage
    const int kN1 = (t0 + 3 < NT) ? t0 + 3 : NT - 1;   //  never read)

    // P1: read A0,B0(buf0); stage (t+1).B1 -> buf1; MFMA Q(0,0)
    readA(0, 0); readB(0, 0, bF[0]);
    stageB(1, 1, kB1);
    BARRIER(); WAIT_LGKM0();
#define CHIDX 0
    MFMAQ(0, bF[0]);
#undef CHIDX
    BARRIER();
    // P2: read B1(buf0); stage (t+2).A0 -> buf0; Q(0,1)
    readB(0, 1, bF[1]);
    stageA(0, 0, kN0);
    BARRIER(); WAIT_LGKM0();
#define CHIDX 1
    MFMAQ(0, bF[1]);
#undef CHIDX
    BARRIER();
    // P3: read A1(buf0); stage (t+2).B0 -> buf0; Q(1,1)
    readA(0, 1);
    stageB(0, 0, kN0);
    BARRIER(); WAIT_LGKM0();
#define CHIDX 1
    MFMAQ(1, bF[1]);
#undef CHIDX
    BARRIER();
    // P4: stage (t+2).A1 -> buf0; counted vmcnt; Q(1,0) (regs)
    stageA(0, 1, kN0);
    WAIT_VM(VN);
    BARRIER();
#define CHIDX 0
    MFMAQ(1, bF[0]);
#undef CHIDX
    BARRIER();
    // P5: read A0,B0(buf1); stage (t+2).B1 -> buf0; Q(0,0)
    readA(1, 0); readB(1, 0, bF[0]);
    stageB(0, 1, kN0);
    BARRIER(); WAIT_LGKM0();
#define CHIDX 0
    MFMAQ(0, bF[0]);
#undef CHIDX
    BARRIER();
    // P6: read B1(buf1); stage (t+3).A0 -> buf1; Q(0,1)
    readB(1, 1, bF[1]);
    stageA(1, 0, kN1);
    BARRIER(); WAIT_LGKM0();
#define CHIDX 1
    MFMAQ(0, bF[1]);
#undef CHIDX
    BARRIER();
    // P7: read A1(buf1); stage (t+3).B0 -> buf1; Q(1,1)
    readA(1, 1);
    stageB(1, 0, kN1);
    BARRIER(); WAIT_LGKM0();
#define CHIDX 1
    MFMAQ(1, bF[1]);
#undef CHIDX
    BARRIER();
    // P8: stage (t+3).A1 -> buf1; counted vmcnt; Q(1,0)
    stageA(1, 1, kN1);
    WAIT_VM(VN);
    BARRIER();
#define CHIDX 0
    MFMAQ(1, bF[0]);
#undef CHIDX
    BARRIER();
  }

  // ---- epilogue. C/D: col = lane&15, row = (lane>>4)*4 + j
  const int rB0 = wr * 128 + grpA * 4;
  const int cB0 = colBase + wc * WNC + rowLane;
#pragma unroll
  for (int m = 0; m < 8; ++m) {
#pragma unroll
    for (int n = 0; n < NACC; ++n) {
#pragma unroll
      for (int j = 0; j < 4; ++j) {
        int r = rB0 + m * 16 + j;
        if (r < rowsValid) {
          size_t idx = (size_t)(rowBase + r) * N_DIM + (cB0 + n * 16);
          float v = accC[m][n][j];
          if (RELU2) {
            v = v > 0.f ? v : 0.f;
            float hb = bf2f(f2bf(v));
            ((unsigned short*)Cout)[idx] = f2bf(hb * hb);
          } else {
            ((float*)Cout)[idx] = bf2f(f2bf(v));
          }
        }
      }
    }
  }
#undef MFMAQ
}

extern "C" void kernel_launch(void* const* d_in, const int* in_sizes, int n_in,
                              void* d_out, int out_size, void* d_ws, size_t ws_size,
                              hipStream_t stream) {
  const float* x   = (const float*)d_in[0];
  const int*   cnt = (const int*)d_in[1];
  const float* wu  = (const float*)d_in[2];
  const float* wd  = (const float*)d_in[3];
  float* out = (float*)d_out;
  char*  ws  = (char*)d_ws;

  unsigned short* xb   = (unsigned short*)(ws);                // 16 MiB
  unsigned short* wub  = (unsigned short*)(ws + (16u << 20));  // 32 MiB
  unsigned short* wdb  = (unsigned short*)(ws + (48u << 20));  // 32 MiB
  unsigned short* hbuf = (unsigned short*)(ws + (80u << 20));  // 32 MiB

  cvt_f32_bf16<<<2048, 256, 0, stream>>>(x,  xb,  T_TOK * D_DIM / 4);
  cvt_f32_bf16<<<2048, 256, 0, stream>>>(wu, wub, E_NUM * H_DIM * D_DIM / 4);
  cvt_f32_bf16<<<2048, 256, 0, stream>>>(wd, wdb, E_NUM * D_DIM * H_DIM / 4);

  // grid.x = max tiles: floor(T/256) + E = 40 (excess blocks exit early)
  gg8<D_DIM, H_DIM, 256, true ><<<dim3(40, H_DIM / 256), dim3(512), 0, stream>>>(
      xb, wub, cnt, (void*)hbuf);
  gg8<H_DIM, D_DIM, 128, false><<<dim3(40, D_DIM / 128), dim3(512), 0, stream>>>(
      hbuf, wdb, cnt, (void*)out);
}

// Round 5
// 126.876 us; speedup vs baseline: 1.3762x; 1.0184x over previous
//
#include <hip/hip_runtime.h>
#include <stdint.h>

constexpr int T_TOK = 8192;
constexpr int D_DIM = 1024;
constexpr int H_DIM = 2048;
constexpr int E_NUM = 8;

typedef __bf16 bf16x8 __attribute__((ext_vector_type(8)));
typedef float  f32x4  __attribute__((ext_vector_type(4)));
typedef unsigned int u32x4 __attribute__((ext_vector_type(4)));

static __device__ __forceinline__ unsigned short f2bf(float f) {
  union { float f; unsigned u; } a; a.f = f;
  unsigned r = a.u + 0x7fffu + ((a.u >> 16) & 1u);   // RNE
  return (unsigned short)(r >> 16);
}
static __device__ __forceinline__ float bf2f(unsigned short h) {
  union { unsigned u; float f; } a; a.u = ((unsigned)h) << 16;
  return a.f;
}

// ---------------- fp32 -> bf16 conversion (x only) ----------------
__global__ void cvt_f32_bf16(const float* __restrict__ src,
                             unsigned short* __restrict__ dst, int n4) {
  int i = blockIdx.x * blockDim.x + threadIdx.x;
  int stride = gridDim.x * blockDim.x;
  for (; i < n4; i += stride) {
    float4 v = reinterpret_cast<const float4*>(src)[i];
    ushort4 o;
    o.x = f2bf(v.x); o.y = f2bf(v.y); o.z = f2bf(v.z); o.w = f2bf(v.w);
    reinterpret_cast<ushort4*>(dst)[i] = o;
  }
}

#define FENCE() asm volatile("" ::: "memory")
#define BARRIER() do { FENCE(); __builtin_amdgcn_s_barrier(); FENCE(); } while (0)
#define WAIT_LGKM0() asm volatile("s_waitcnt lgkmcnt(0)" ::: "memory")
#define WAIT_VM(N) asm volatile("s_waitcnt vmcnt(%0)" :: "i"(N) : "memory")
// Rule #18: register-only consumers of inline-asm load results can be hoisted
// above an inline-asm s_waitcnt ("memory" clobber does not order them).
// sched_barrier(0) right after the wait pins them below it.
#define SCHED_FENCE() __builtin_amdgcn_sched_barrier(0)

static __device__ __forceinline__ f32x4 gload4(const void* p) {
  f32x4 r;
  asm volatile("global_load_dwordx4 %0, %1, off" : "=v"(r) : "v"(p) : "memory");
  return r;
}

// ---- 8-phase grouped GEMM with FUSED B fp32->bf16 conversion (reg-staged) ----
// A: (T,K) bf16 rm (gload_lds staging). B: (E,N,K) fp32 rm, converted in-reg.
// C = A @ B[e]^T per expert segment.
//
// Cross-wave LDS ordering invariant: every global_load_lds is self-drained by
// its issuing wave BEFORE a barrier that precedes any wave's read of that
// region.  A0: drained by WAIT_VM(2) before P4-end barrier (read next-P1).
// A1: drained by WAIT_VM(2BL+2) before P2-end barrier of the NEXT iteration
// (read next-P3).  B ds_writes: committed by WAIT_LGKM0 before their phase-end
// barrier (read next-P1).
template <int K_DIM, int N_DIM, int BN, bool RELU2>
__global__ __launch_bounds__(512, 2)
void gg8(const unsigned short* __restrict__ A,
         const float* __restrict__ Bw,
         const int* __restrict__ counts,
         void* __restrict__ Cout) {
  constexpr int BM = 256, BK = 64;
  constexpr int NT = K_DIM / BK;
  constexpr int WNC = BN / 4;          // per-wave output cols
  constexpr int NACC = WNC / 16;       // 4 (BN=256) or 2 (BN=128)
  constexpr int NQN = NACC / 2;        // 2 or 1
  constexpr int BL = (BN == 256) ? 4 : 2;   // dwordx4 loads per B-half/thread
  constexpr int TSH = (BN == 256) ? 2 : 3;  // tid shift for B row
  constexpr int FPB = BL * 16;              // fp32 bytes per thread per half

  const int tid  = threadIdx.x;
  const int wid  = tid >> 6;
  const int lane = tid & 63;
  const int wr   = wid >> 2;
  const int wc   = wid & 3;

  // ---- blockIdx.x -> (expert, 256-row tile)
  int t = blockIdx.x;
  int e = -1, rowBase = 0, rowsValid = 0;
  {
    int tiles = 0, off = 0;
#pragma unroll
    for (int i = 0; i < E_NUM; ++i) {
      int n  = counts[i];
      int nt = (n + BM - 1) / BM;
      if (e < 0 && t < tiles + nt) {
        e = i;
        int lt = t - tiles;
        rowBase   = off + lt * BM;
        rowsValid = n - lt * BM;
        if (rowsValid > BM) rowsValid = BM;
      }
      tiles += nt; off += n;
    }
  }
  if (e < 0) return;
  const int colBase = blockIdx.y * BN;

  __shared__ __align__(1024) char lds[(BM + BN) * BK * 2 * 2];  // 128/96 KiB
  auto ldsA = [&](int b) -> char* { return lds + b * (BM * 128); };
  auto ldsB = [&](int b) -> char* { return lds + 2 * (BM * 128) + b * (BN * 128); };

  const char* gA = (const char*)A + (size_t)rowBase * (K_DIM * 2);
  // fp32 B source, per-thread fixed row/byte offset
  const int  bRow0 = tid >> TSH;                        // row within half
  const int  bByte = (tid & ((1 << TSH) - 1)) * FPB;    // byte offset in row
  const char* gBbase = (const char*)Bw +
      ((size_t)e * N_DIM + colBase) * (size_t)(K_DIM * 4);

  const int lr8 = lane >> 3;
  const int gsw = (lane & 7) ^ lr8;    // inverse-swizzled source granule (A)

  auto stageA = [&](int buf, int alpha, int kt) {
#pragma unroll
    for (int j = 0; j < 2; ++j) {
      int bi   = j * 8 + wid;
      int row0 = (bi >> 3) * 128 + alpha * 64 + (bi & 7) * 8;
      int sr   = row0 + lr8;
      if (sr >= rowsValid) sr = rowsValid - 1;
      const char* src = gA + (size_t)sr * (K_DIM * 2) + (size_t)kt * 128 + gsw * 16;
      __builtin_amdgcn_global_load_lds(
          (const __attribute__((address_space(1))) void*)src,
          (__attribute__((address_space(3))) void*)(ldsA(buf) + row0 * 128),
          16, 0, 0);
    }
  };

  // issue the BL fp32 loads for B half h of K-tile kt
  auto loadBhalf = [&](f32x4 (&q)[BL], int h, int kt) {
    const char* s = gBbase + (size_t)(h * (BN / 2) + bRow0) * (K_DIM * 4)
                  + (size_t)kt * 256 + bByte;
#pragma unroll
    for (int j = 0; j < BL; ++j) q[j] = gload4(s + j * 16);
  };
  // convert + swizzled LDS write of B half h into buffer buf
  auto writeBhalf = [&](int buf, const f32x4 (&q)[BL], int h) {
    const int row = h * (BN / 2) + bRow0;
    char* base = ldsB(buf) + row * 128;
    const int rs = row & 7;
#pragma unroll
    for (int c = 0; c < BL / 2; ++c) {        // one 16B granule per 2 loads
      u32x4 w;
#pragma unroll
      for (int k = 0; k < 2; ++k) {
        const f32x4& v = q[c * 2 + k];
#pragma unroll
        for (int p = 0; p < 2; ++p) {
          unsigned lo = f2bf(v[p * 2]), hi = f2bf(v[p * 2 + 1]);
          w[k * 2 + p] = lo | (hi << 16);
        }
      }
      // granule index within the 128B row (8 granules)
      int g = (BN == 256) ? (2 * (tid & 3) + c) : (tid & 7);
      *reinterpret_cast<u32x4*>(base + (g ^ rs) * 16) = w;
    }
  };

  const int rowLane = lane & 15;
  const int grpA    = lane >> 4;
  const int swzm    = lane & 7;

  bf16x8 aF[4][2];
  bf16x8 bF0[NQN][2], bF1[NQN][2];
  f32x4  accC[8][NACC];
#pragma unroll
  for (int m = 0; m < 8; ++m)
#pragma unroll
    for (int n = 0; n < NACC; ++n) accC[m][n] = (f32x4){0.f, 0.f, 0.f, 0.f};

  auto readA = [&](int buf, int rh) {
    const char* base = ldsA(buf) + (wr * 128 + rh * 64 + rowLane) * 128;
#pragma unroll
    for (int m = 0; m < 4; ++m)
#pragma unroll
      for (int ks = 0; ks < 2; ++ks) {
        int g = (ks * 4 + grpA) ^ swzm;
        aF[m][ks] = *(const bf16x8*)(base + m * (16 * 128) + g * 16);
      }
  };
  auto readB = [&](int buf, int ch, bf16x8 (&dst)[NQN][2]) {
    const char* base = ldsB(buf) + (wc * WNC + ch * (WNC / 2) + rowLane) * 128;
#pragma unroll
    for (int n = 0; n < NQN; ++n)
#pragma unroll
      for (int ks = 0; ks < 2; ++ks) {
        int g = (ks * 4 + grpA) ^ swzm;
        dst[n][ks] = *(const bf16x8*)(base + n * (16 * 128) + g * 16);
      }
  };

#define MFMAQ(RH, CH, BFA)                                                    \
  do {                                                                        \
    __builtin_amdgcn_s_setprio(1);                                            \
    _Pragma("unroll")                                                         \
    for (int m_ = 0; m_ < 4; ++m_) {                                          \
      _Pragma("unroll")                                                       \
      for (int n_ = 0; n_ < NQN; ++n_) {                                      \
        f32x4 c_ = accC[(RH) * 4 + m_][(CH) * NQN + n_];                      \
        c_ = __builtin_amdgcn_mfma_f32_16x16x32_bf16(aF[m_][0], BFA[n_][0], c_, 0, 0, 0); \
        c_ = __builtin_amdgcn_mfma_f32_16x16x32_bf16(aF[m_][1], BFA[n_][1], c_, 0, 0, 0); \
        accC[(RH) * 4 + m_][(CH) * NQN + n_] = c_;                            \
      }                                                                       \
    }                                                                         \
    __builtin_amdgcn_s_setprio(0);                                            \
  } while (0)

  f32x4 bq0[BL], bq1[BL];

  // ---- prologue: tile 0 into buf0 (fully drained -> no races at t2=0)
  loadBhalf(bq0, 0, 0);
  loadBhalf(bq1, 1, 0);
  stageA(0, 0, 0); stageA(0, 1, 0);
  WAIT_VM(BL + 4);  SCHED_FENCE();  writeBhalf(0, bq0, 0);
  WAIT_VM(4);       SCHED_FENCE();  writeBhalf(0, bq1, 1);
  WAIT_VM(0); WAIT_LGKM0();
  BARRIER();

  for (int t2 = 0; t2 < NT; ++t2) {
    const int cur = t2 & 1, nxt = cur ^ 1;
    const int ktn = (t2 + 1 < NT) ? t2 + 1 : NT - 1;   // tail: harmless re-stage

    // P1: issue B-half0(t+1); read A0,B0(cur); MFMA Q(0,0)
    loadBhalf(bq0, 0, ktn);
    readA(cur, 0); readB(cur, 0, bF0);
    BARRIER(); WAIT_LGKM0();
    MFMAQ(0, 0, bF0);
    BARRIER();

    // P2: issue B-half1(t+1); gload A0(t+1)->nxt; read B1(cur); Q(0,1);
    //     drain A1(cur) [issued prev-P3] before end barrier -> P3 reads safe
    loadBhalf(bq1, 1, ktn);
    stageA(nxt, 0, ktn);
    readB(cur, 1, bF1);
    BARRIER(); WAIT_LGKM0();
    MFMAQ(0, 1, bF1);
    WAIT_VM(2 * BL + 2);
    BARRIER();

    // P3: vm-wait bq0; cvt+write bh0->nxt; gload A1(t+1)->nxt; read A1(cur); Q(1,1)
    WAIT_VM(BL + 2);
    SCHED_FENCE();
    writeBhalf(nxt, bq0, 0);
    stageA(nxt, 1, ktn);
    readA(cur, 1);
    BARRIER(); WAIT_LGKM0();
    MFMAQ(1, 1, bF1);
    BARRIER();

    // P4: vm-wait bq1; cvt+write bh1->nxt; drain A0(t+1); Q(1,0)
    WAIT_VM(4);
    SCHED_FENCE();
    writeBhalf(nxt, bq1, 1);
    WAIT_VM(2);
    BARRIER(); WAIT_LGKM0();   // commits this wave's ds_writes before barrier 2
    MFMAQ(1, 0, bF0);
    BARRIER();
  }

  // ---- epilogue. C/D: col = lane&15, row = (lane>>4)*4 + j
  const int rB0 = wr * 128 + grpA * 4;
  const int cB0 = colBase + wc * WNC + rowLane;
#pragma unroll
  for (int m = 0; m < 8; ++m) {
#pragma unroll
    for (int n = 0; n < NACC; ++n) {
#pragma unroll
      for (int j = 0; j < 4; ++j) {
        int r = rB0 + m * 16 + j;
        if (r < rowsValid) {
          size_t idx = (size_t)(rowBase + r) * N_DIM + (cB0 + n * 16);
          float v = accC[m][n][j];
          if (RELU2) {
            v = v > 0.f ? v : 0.f;
            float hb = bf2f(f2bf(v));
            ((unsigned short*)Cout)[idx] = f2bf(hb * hb);
          } else {
            ((float*)Cout)[idx] = bf2f(f2bf(v));
          }
        }
      }
    }
  }
#undef MFMAQ
}

extern "C" void kernel_launch(void* const* d_in, const int* in_sizes, int n_in,
                              void* d_out, int out_size, void* d_ws, size_t ws_size,
                              hipStream_t stream) {
  const float* x   = (const float*)d_in[0];
  const int*   cnt = (const int*)d_in[1];
  const float* wu  = (const float*)d_in[2];
  const float* wd  = (const float*)d_in[3];
  float* out = (float*)d_out;
  char*  ws  = (char*)d_ws;

  unsigned short* xb   = (unsigned short*)(ws);                // 16 MiB
  unsigned short* hbuf = (unsigned short*)(ws + (16u << 20));  // 32 MiB

  cvt_f32_bf16<<<2048, 256, 0, stream>>>(x, xb, T_TOK * D_DIM / 4);

  // grid.x = max tiles: floor(T/256) + E = 40 (excess blocks exit early)
  gg8<D_DIM, H_DIM, 256, true ><<<dim3(40, H_DIM / 256), dim3(512), 0, stream>>>(
      xb, wu, cnt, (void*)hbuf);
  gg8<H_DIM, D_DIM, 128, false><<<dim3(40, D_DIM / 128), dim3(512), 0, stream>>>(
      hbuf, wd, cnt, (void*)out);
}

// Round 7
// 115.455 us; speedup vs baseline: 1.5124x; 1.0989x over previous
//
#include <hip/hip_runtime.h>
#include <stdint.h>

constexpr int T_TOK = 8192;
constexpr int D_DIM = 1024;
constexpr int H_DIM = 2048;
constexpr int E_NUM = 8;

typedef __bf16 bf16x8 __attribute__((ext_vector_type(8)));
typedef float  f32x4  __attribute__((ext_vector_type(4)));
typedef unsigned int u32x4 __attribute__((ext_vector_type(4)));

static __device__ __forceinline__ unsigned short f2bf(float f) {
  union { float f; unsigned u; } a; a.f = f;
  unsigned r = a.u + 0x7fffu + ((a.u >> 16) & 1u);   // RNE
  return (unsigned short)(r >> 16);
}
static __device__ __forceinline__ float bf2f(unsigned short h) {
  union { unsigned u; float f; } a; a.u = ((unsigned)h) << 16;
  return a.f;
}

// ---------------- fp32 -> bf16 conversion (x only) ----------------
__global__ void cvt_f32_bf16(const float* __restrict__ src,
                             unsigned short* __restrict__ dst, int n4) {
  int i = blockIdx.x * blockDim.x + threadIdx.x;
  int stride = gridDim.x * blockDim.x;
  for (; i < n4; i += stride) {
    float4 v = reinterpret_cast<const float4*>(src)[i];
    ushort4 o;
    o.x = f2bf(v.x); o.y = f2bf(v.y); o.z = f2bf(v.z); o.w = f2bf(v.w);
    reinterpret_cast<ushort4*>(dst)[i] = o;
  }
}

#define FENCE() asm volatile("" ::: "memory")
#define BARRIER() do { FENCE(); __builtin_amdgcn_s_barrier(); FENCE(); } while (0)
#define WAIT_LGKM0() asm volatile("s_waitcnt lgkmcnt(0)" ::: "memory")
#define WAIT_VM(N) asm volatile("s_waitcnt vmcnt(%0)" :: "i"(N) : "memory")
// Rule #18: register-only consumers of inline-asm load results can be hoisted
// above an inline-asm s_waitcnt. sched_barrier(0) pins them below the wait.
#define SCHED_FENCE() __builtin_amdgcn_sched_barrier(0)

static __device__ __forceinline__ f32x4 gload4(const void* p) {
  f32x4 r;
  asm volatile("global_load_dwordx4 %0, %1, off" : "=v"(r) : "v"(p) : "memory");
  return r;
}

// ---- 4-phase grouped GEMM, fused B fp32->bf16, DEEP pipeline ----
// A: (T,K) bf16 rm via global_load_lds (both halves issued at P1, drained P4).
// B: (E,N,K) fp32, reg-staged: load(t+2) issued at P3/P4 right after the regs
// are freed by the convert+write of tile t+1 -> 4-phase issue->drain distance.
//
// FIFO vmcnt ledger (steady state, outstanding at iter start = 2BL {c0,c1}):
//   P1: +4 A-stages                          {c0,c1,A4}
//   P3: vm(BL+4) drains c0; write c0; +nc0   {c1,A4,nc0}
//   P4: vm(BL+4) drains c1; write c1; +nc1; vm(2BL) drains A4  -> {nc0,nc1}
// B ds_writes commit via own lgkm0 before each phase-end barrier; consumed
// >=2 barriers later. A drained before P4-end barrier; consumed next-P1.
//
// EPILOGUE HAZARD (round-6 lesson): the final iteration's reloads are never
// consumed -> dest regs look dead -> allocator may reuse them for epilogue
// temps while the loads are still in flight; the late writeback clobbers
// them. Fix: drain vmcnt to 0 after the loop and keep the dest regs alive
// across the drain with an empty asm consumer.
template <int K_DIM, int N_DIM, int BN, bool RELU2>
__global__ __launch_bounds__(512, 2)
void gg8(const unsigned short* __restrict__ A,
         const float* __restrict__ Bw,
         const int* __restrict__ counts,
         void* __restrict__ Cout) {
  constexpr int BM = 256, BK = 64;
  constexpr int NT = K_DIM / BK;
  constexpr int WNC = BN / 4;          // per-wave output cols
  constexpr int NACC = WNC / 16;       // 4 (BN=256) or 2 (BN=128)
  constexpr int NQN = NACC / 2;        // 2 or 1
  constexpr int BL = (BN == 256) ? 4 : 2;   // dwordx4 loads per B-half/thread
  constexpr int TSH = (BN == 256) ? 2 : 3;  // tid shift for B row
  constexpr int FPB = BL * 16;              // fp32 bytes per thread per half

  const int tid  = threadIdx.x;
  const int wid  = tid >> 6;
  const int lane = tid & 63;
  const int wr   = wid >> 2;
  const int wc   = wid & 3;

  // ---- blockIdx.x -> (expert, 256-row tile)
  int t = blockIdx.x;
  int e = -1, rowBase = 0, rowsValid = 0;
  {
    int tiles = 0, off = 0;
#pragma unroll
    for (int i = 0; i < E_NUM; ++i) {
      int n  = counts[i];
      int nt = (n + BM - 1) / BM;
      if (e < 0 && t < tiles + nt) {
        e = i;
        int lt = t - tiles;
        rowBase   = off + lt * BM;
        rowsValid = n - lt * BM;
        if (rowsValid > BM) rowsValid = BM;
      }
      tiles += nt; off += n;
    }
  }
  if (e < 0) return;
  const int colBase = blockIdx.y * BN;

  __shared__ __align__(1024) char lds[(BM + BN) * BK * 2 * 2];  // 128/96 KiB
  auto ldsA = [&](int b) -> char* { return lds + b * (BM * 128); };
  auto ldsB = [&](int b) -> char* { return lds + 2 * (BM * 128) + b * (BN * 128); };

  const char* gA = (const char*)A + (size_t)rowBase * (K_DIM * 2);
  const int  bRow0 = tid >> TSH;                        // B row within half
  const int  bByte = (tid & ((1 << TSH) - 1)) * FPB;    // byte offset in row
  const char* gBbase = (const char*)Bw +
      ((size_t)e * N_DIM + colBase) * (size_t)(K_DIM * 4);

  const int lr8 = lane >> 3;
  const int gsw = (lane & 7) ^ lr8;    // inverse-swizzled source granule (A)

  auto stageA = [&](int buf, int alpha, int kt) {
#pragma unroll
    for (int j = 0; j < 2; ++j) {
      int bi   = j * 8 + wid;
      int row0 = (bi >> 3) * 128 + alpha * 64 + (bi & 7) * 8;
      int sr   = row0 + lr8;
      if (sr >= rowsValid) sr = rowsValid - 1;
      const char* src = gA + (size_t)sr * (K_DIM * 2) + (size_t)kt * 128 + gsw * 16;
      __builtin_amdgcn_global_load_lds(
          (const __attribute__((address_space(1))) void*)src,
          (__attribute__((address_space(3))) void*)(ldsA(buf) + row0 * 128),
          16, 0, 0);
    }
  };

  auto loadBhalf = [&](f32x4 (&q)[BL], int h, int kt) {
    const char* s = gBbase + (size_t)(h * (BN / 2) + bRow0) * (K_DIM * 4)
                  + (size_t)kt * 256 + bByte;
#pragma unroll
    for (int j = 0; j < BL; ++j) q[j] = gload4(s + j * 16);
  };
  auto writeBhalf = [&](int buf, const f32x4 (&q)[BL], int h) {
    const int row = h * (BN / 2) + bRow0;
    char* base = ldsB(buf) + row * 128;
    const int rs = row & 7;
#pragma unroll
    for (int c = 0; c < BL / 2; ++c) {        // one 16B granule per 2 loads
      u32x4 w;
#pragma unroll
      for (int k = 0; k < 2; ++k) {
        const f32x4& v = q[c * 2 + k];
#pragma unroll
        for (int p = 0; p < 2; ++p) {
          unsigned lo = f2bf(v[p * 2]), hi = f2bf(v[p * 2 + 1]);
          w[k * 2 + p] = lo | (hi << 16);
        }
      }
      int g = (BN == 256) ? (2 * (tid & 3) + c) : (tid & 7);
      *reinterpret_cast<u32x4*>(base + (g ^ rs) * 16) = w;
    }
  };

  const int rowLane = lane & 15;
  const int grpA    = lane >> 4;
  const int swzm    = lane & 7;

  bf16x8 aF[4][2];
  bf16x8 bF0[NQN][2], bF1[NQN][2];
  f32x4  accC[8][NACC];
#pragma unroll
  for (int m = 0; m < 8; ++m)
#pragma unroll
    for (int n = 0; n < NACC; ++n) accC[m][n] = (f32x4){0.f, 0.f, 0.f, 0.f};

  auto readA = [&](int buf, int rh) {
    const char* base = ldsA(buf) + (wr * 128 + rh * 64 + rowLane) * 128;
#pragma unroll
    for (int m = 0; m < 4; ++m)
#pragma unroll
      for (int ks = 0; ks < 2; ++ks) {
        int g = (ks * 4 + grpA) ^ swzm;
        aF[m][ks] = *(const bf16x8*)(base + m * (16 * 128) + g * 16);
      }
  };
  auto readB = [&](int buf, int ch, bf16x8 (&dst)[NQN][2]) {
    const char* base = ldsB(buf) + (wc * WNC + ch * (WNC / 2) + rowLane) * 128;
#pragma unroll
    for (int n = 0; n < NQN; ++n)
#pragma unroll
      for (int ks = 0; ks < 2; ++ks) {
        int g = (ks * 4 + grpA) ^ swzm;
        dst[n][ks] = *(const bf16x8*)(base + n * (16 * 128) + g * 16);
      }
  };

#define MFMAQ(RH, CH, BFA)                                                    \
  do {                                                                        \
    __builtin_amdgcn_s_setprio(1);                                            \
    _Pragma("unroll")                                                         \
    for (int m_ = 0; m_ < 4; ++m_) {                                          \
      _Pragma("unroll")                                                       \
      for (int n_ = 0; n_ < NQN; ++n_) {                                      \
        f32x4 c_ = accC[(RH) * 4 + m_][(CH) * NQN + n_];                      \
        c_ = __builtin_amdgcn_mfma_f32_16x16x32_bf16(aF[m_][0], BFA[n_][0], c_, 0, 0, 0); \
        c_ = __builtin_amdgcn_mfma_f32_16x16x32_bf16(aF[m_][1], BFA[n_][1], c_, 0, 0, 0); \
        accC[(RH) * 4 + m_][(CH) * NQN + n_] = c_;                            \
      }                                                                       \
    }                                                                         \
    __builtin_amdgcn_s_setprio(0);                                            \
  } while (0)

  f32x4 bq0[BL], bq1[BL];

  // ---- prologue: tile0 -> buf0; leave tile1 B loads in flight (2BL)
  loadBhalf(bq0, 0, 0);
  loadBhalf(bq1, 1, 0);
  stageA(0, 0, 0); stageA(0, 1, 0);
  WAIT_VM(BL + 4); SCHED_FENCE();
  writeBhalf(0, bq0, 0);
  loadBhalf(bq0, 0, 1);
  WAIT_VM(BL + 4); SCHED_FENCE();
  writeBhalf(0, bq1, 1);
  loadBhalf(bq1, 1, 1);
  WAIT_VM(2 * BL);
  WAIT_LGKM0();
  BARRIER();

  for (int t2 = 0; t2 < NT; ++t2) {
    const int cur = t2 & 1, nxt = cur ^ 1;
    const int ktn  = (t2 + 1 < NT) ? t2 + 1 : NT - 1;  // A tile t+1
    const int ktn2 = (t2 + 2 < NT) ? t2 + 2 : NT - 1;  // B tile t+2 (tail: re-read)

    // P1: stage BOTH A halves (t+1)->nxt; read A0,B0(cur); MFMA Q(0,0)
    stageA(nxt, 0, ktn);
    stageA(nxt, 1, ktn);
    readA(cur, 0); readB(cur, 0, bF0);
    BARRIER(); WAIT_LGKM0();
    MFMAQ(0, 0, bF0);
    BARRIER();

    // P2: read B1(cur); MFMA Q(0,1)
    readB(cur, 1, bF1);
    BARRIER(); WAIT_LGKM0();
    MFMAQ(0, 1, bF1);
    BARRIER();

    // P3: drain c0 (issued prev-P3, 4 phases ago); cvt+write b-half0 -> nxt;
    //     immediately reload freed regs with (t+2) half0; read A1(cur); Q(1,1)
    WAIT_VM(BL + 4);
    SCHED_FENCE();
    writeBhalf(nxt, bq0, 0);
    loadBhalf(bq0, 0, ktn2);
    readA(cur, 1);
    BARRIER(); WAIT_LGKM0();
    MFMAQ(1, 1, bF1);
    BARRIER();

    // P4: drain c1; cvt+write b-half1 -> nxt; reload (t+2) half1;
    //     drain A stages (issued this P1) before publishing barrier; Q(1,0)
    WAIT_VM(BL + 4);
    SCHED_FENCE();
    writeBhalf(nxt, bq1, 1);
    loadBhalf(bq1, 1, ktn2);
    WAIT_VM(2 * BL);
    BARRIER(); WAIT_LGKM0();   // commits this wave's ds_writes before barrier 2
    MFMAQ(1, 0, bF0);
    BARRIER();
  }

  // ---- drain in-flight (never-consumed) reloads BEFORE the epilogue can
  // reuse their dest registers; keep-alive pins liveness across the drain.
  WAIT_VM(0);
  SCHED_FENCE();
#pragma unroll
  for (int j = 0; j < BL; ++j) {
    asm volatile("" :: "v"(bq0[j]), "v"(bq1[j]));
  }

  // ---- epilogue. C/D: col = lane&15, row = (lane>>4)*4 + j
  const int rB0 = wr * 128 + grpA * 4;
  const int cB0 = colBase + wc * WNC + rowLane;
#pragma unroll
  for (int m = 0; m < 8; ++m) {
#pragma unroll
    for (int n = 0; n < NACC; ++n) {
#pragma unroll
      for (int j = 0; j < 4; ++j) {
        int r = rB0 + m * 16 + j;
        if (r < rowsValid) {
          size_t idx = (size_t)(rowBase + r) * N_DIM + (cB0 + n * 16);
          float v = accC[m][n][j];
          if (RELU2) {
            v = v > 0.f ? v : 0.f;
            float hb = bf2f(f2bf(v));
            ((unsigned short*)Cout)[idx] = f2bf(hb * hb);
          } else {
            ((float*)Cout)[idx] = bf2f(f2bf(v));
          }
        }
      }
    }
  }
#undef MFMAQ
}

extern "C" void kernel_launch(void* const* d_in, const int* in_sizes, int n_in,
                              void* d_out, int out_size, void* d_ws, size_t ws_size,
                              hipStream_t stream) {
  const float* x   = (const float*)d_in[0];
  const int*   cnt = (const int*)d_in[1];
  const float* wu  = (const float*)d_in[2];
  const float* wd  = (const float*)d_in[3];
  float* out = (float*)d_out;
  char*  ws  = (char*)d_ws;

  unsigned short* xb   = (unsigned short*)(ws);                // 16 MiB
  unsigned short* hbuf = (unsigned short*)(ws + (16u << 20));  // 32 MiB

  cvt_f32_bf16<<<2048, 256, 0, stream>>>(x, xb, T_TOK * D_DIM / 4);

  // grid.x = max tiles: floor(T/256) + E = 40 (excess blocks exit early)
  gg8<D_DIM, H_DIM, 256, true ><<<dim3(40, H_DIM / 256), dim3(512), 0, stream>>>(
      xb, wu, cnt, (void*)hbuf);
  gg8<H_DIM, D_DIM, 128, false><<<dim3(40, D_DIM / 128), dim3(512), 0, stream>>>(
      hbuf, wd, cnt, (void*)out);
}

// Round 8
// 113.738 us; speedup vs baseline: 1.5352x; 1.0151x over previous
//
#include <hip/hip_runtime.h>
#include <stdint.h>

constexpr int T_TOK = 8192;
constexpr int D_DIM = 1024;
constexpr int H_DIM = 2048;
constexpr int E_NUM = 8;

typedef __bf16 bf16x8 __attribute__((ext_vector_type(8)));
typedef float  f32x4  __attribute__((ext_vector_type(4)));
typedef unsigned int u32x4 __attribute__((ext_vector_type(4)));

static __device__ __forceinline__ unsigned short f2bf(float f) {
  union { float f; unsigned u; } a; a.f = f;
  unsigned r = a.u + 0x7fffu + ((a.u >> 16) & 1u);   // RNE
  return (unsigned short)(r >> 16);
}

// ---------------- fp32 -> bf16 conversion (x only) ----------------
__global__ void cvt_f32_bf16(const float* __restrict__ src,
                             unsigned short* __restrict__ dst, int n4) {
  int i = blockIdx.x * blockDim.x + threadIdx.x;
  int stride = gridDim.x * blockDim.x;
  for (; i < n4; i += stride) {
    float4 v = reinterpret_cast<const float4*>(src)[i];
    ushort4 o;
    o.x = f2bf(v.x); o.y = f2bf(v.y); o.z = f2bf(v.z); o.w = f2bf(v.w);
    reinterpret_cast<ushort4*>(dst)[i] = o;
  }
}

#define FENCE() asm volatile("" ::: "memory")
#define BARRIER() do { FENCE(); __builtin_amdgcn_s_barrier(); FENCE(); } while (0)
#define WAIT_LGKM0() asm volatile("s_waitcnt lgkmcnt(0)" ::: "memory")
#define WAIT_VM(N) asm volatile("s_waitcnt vmcnt(%0)" :: "i"(N) : "memory")
#define SCHED_FENCE() __builtin_amdgcn_sched_barrier(0)

static __device__ __forceinline__ f32x4 gload4(const void* p) {
  f32x4 r;
  asm volatile("global_load_dwordx4 %0, %1, off" : "=v"(r) : "v"(p) : "memory");
  return r;
}

// ---- grouped GEMM, fused B fp32->bf16 (reg-staged), deep pipeline ----
// BN==256: 4-phase schedule (16 MFMA/phase). BN==128: merged 2-phase
// (16 MFMA/phase, both col-quadrants per phase) -> half the barriers.
// vmcnt FIFO ledgers verified oldest-first for both BL=4 and BL=2.
template <int K_DIM, int N_DIM, int BN, bool RELU2>
__global__ __launch_bounds__(512, 2)
void gg8(const unsigned short* __restrict__ A,
         const float* __restrict__ Bw,
         const int* __restrict__ counts,
         void* __restrict__ Cout) {
  constexpr int BM = 256, BK = 64;
  constexpr int NT = K_DIM / BK;
  constexpr int WNC = BN / 4;          // per-wave output cols
  constexpr int NACC = WNC / 16;       // 4 (BN=256) or 2 (BN=128)
  constexpr int NQN = NACC / 2;        // 2 or 1
  constexpr int BL = (BN == 256) ? 4 : 2;   // dwordx4 loads per B-half/thread
  constexpr int TSH = (BN == 256) ? 2 : 3;  // tid shift for B row
  constexpr int FPB = BL * 16;              // fp32 bytes per thread per half

  const int tid  = threadIdx.x;
  const int wid  = tid >> 6;
  const int lane = tid & 63;
  const int wr   = wid >> 2;
  const int wc   = wid & 3;

  // ---- blockIdx.x -> (expert, 256-row tile)
  int t = blockIdx.x;
  int e = -1, rowBase = 0, rowsValid = 0;
  {
    int tiles = 0, off = 0;
#pragma unroll
    for (int i = 0; i < E_NUM; ++i) {
      int n  = counts[i];
      int nt = (n + BM - 1) / BM;
      if (e < 0 && t < tiles + nt) {
        e = i;
        int lt = t - tiles;
        rowBase   = off + lt * BM;
        rowsValid = n - lt * BM;
        if (rowsValid > BM) rowsValid = BM;
      }
      tiles += nt; off += n;
    }
  }
  if (e < 0) return;
  const int colBase = blockIdx.y * BN;

  __shared__ __align__(1024) char lds[(BM + BN) * BK * 2 * 2];  // 128/96 KiB
  auto ldsA = [&](int b) -> char* { return lds + b * (BM * 128); };
  auto ldsB = [&](int b) -> char* { return lds + 2 * (BM * 128) + b * (BN * 128); };

  const char* gA = (const char*)A + (size_t)rowBase * (K_DIM * 2);
  const int  bRow0 = tid >> TSH;                        // B row within half
  const int  bByte = (tid & ((1 << TSH) - 1)) * FPB;    // byte offset in row
  const char* gBbase = (const char*)Bw +
      ((size_t)e * N_DIM + colBase) * (size_t)(K_DIM * 4);

  const int lr8 = lane >> 3;
  const int gsw = (lane & 7) ^ lr8;    // inverse-swizzled source granule (A)

  auto stageA = [&](int buf, int alpha, int kt) {
#pragma unroll
    for (int j = 0; j < 2; ++j) {
      int bi   = j * 8 + wid;
      int row0 = (bi >> 3) * 128 + alpha * 64 + (bi & 7) * 8;
      int sr   = row0 + lr8;
      if (sr >= rowsValid) sr = rowsValid - 1;
      const char* src = gA + (size_t)sr * (K_DIM * 2) + (size_t)kt * 128 + gsw * 16;
      __builtin_amdgcn_global_load_lds(
          (const __attribute__((address_space(1))) void*)src,
          (__attribute__((address_space(3))) void*)(ldsA(buf) + row0 * 128),
          16, 0, 0);
    }
  };

  auto loadBhalf = [&](f32x4 (&q)[BL], int h, int kt) {
    const char* s = gBbase + (size_t)(h * (BN / 2) + bRow0) * (K_DIM * 4)
                  + (size_t)kt * 256 + bByte;
#pragma unroll
    for (int j = 0; j < BL; ++j) q[j] = gload4(s + j * 16);
  };
  // convert (native casts -> compiler emits v_cvt_pk_bf16_f32) + swizzled write
  auto writeBhalf = [&](int buf, const f32x4 (&q)[BL], int h) {
    const int row = h * (BN / 2) + bRow0;
    char* base = ldsB(buf) + row * 128;
    const int rs = row & 7;
#pragma unroll
    for (int c = 0; c < BL / 2; ++c) {        // one 16B granule per 2 loads
      union { __bf16 b[8]; u32x4 w; } u;
#pragma unroll
      for (int k = 0; k < 2; ++k)
#pragma unroll
        for (int p = 0; p < 4; ++p)
          u.b[k * 4 + p] = (__bf16)q[c * 2 + k][p];
      int g = (BN == 256) ? (2 * (tid & 3) + c) : (tid & 7);
      *reinterpret_cast<u32x4*>(base + (g ^ rs) * 16) = u.w;
    }
  };

  const int rowLane = lane & 15;
  const int grpA    = lane >> 4;
  const int swzm    = lane & 7;

  bf16x8 aF[4][2];
  f32x4  accC[8][NACC];
#pragma unroll
  for (int m = 0; m < 8; ++m)
#pragma unroll
    for (int n = 0; n < NACC; ++n) accC[m][n] = (f32x4){0.f, 0.f, 0.f, 0.f};

  auto readA = [&](int buf, int rh) {
    const char* base = ldsA(buf) + (wr * 128 + rh * 64 + rowLane) * 128;
#pragma unroll
    for (int m = 0; m < 4; ++m)
#pragma unroll
      for (int ks = 0; ks < 2; ++ks) {
        int g = (ks * 4 + grpA) ^ swzm;
        aF[m][ks] = *(const bf16x8*)(base + m * (16 * 128) + g * 16);
      }
  };

  f32x4 bq0[BL], bq1[BL];

  // ---- prologue: tile0 -> buf0; leave tile1 B loads in flight (2BL)
  loadBhalf(bq0, 0, 0);
  loadBhalf(bq1, 1, 0);
  stageA(0, 0, 0); stageA(0, 1, 0);
  WAIT_VM(BL + 4); SCHED_FENCE();
  writeBhalf(0, bq0, 0);
  loadBhalf(bq0, 0, 1);
  WAIT_VM(BL + 4); SCHED_FENCE();
  writeBhalf(0, bq1, 1);
  loadBhalf(bq1, 1, 1);
  WAIT_VM(2 * BL);
  WAIT_LGKM0();
  BARRIER();

  if constexpr (BN == 256) {
    // ---------------- 4-phase schedule (GEMM1) ----------------
    bf16x8 bF0[NQN][2], bF1[NQN][2];
    auto readB = [&](int buf, int ch, bf16x8 (&dst)[NQN][2]) {
      const char* base = ldsB(buf) + (wc * WNC + ch * (WNC / 2) + rowLane) * 128;
#pragma unroll
      for (int n = 0; n < NQN; ++n)
#pragma unroll
        for (int ks = 0; ks < 2; ++ks) {
          int g = (ks * 4 + grpA) ^ swzm;
          dst[n][ks] = *(const bf16x8*)(base + n * (16 * 128) + g * 16);
        }
    };
#define MFMAQ(RH, CH, BFA)                                                    \
  do {                                                                        \
    __builtin_amdgcn_s_setprio(1);                                            \
    _Pragma("unroll")                                                         \
    for (int m_ = 0; m_ < 4; ++m_) {                                          \
      _Pragma("unroll")                                                       \
      for (int n_ = 0; n_ < NQN; ++n_) {                                      \
        f32x4 c_ = accC[(RH) * 4 + m_][(CH) * NQN + n_];                      \
        c_ = __builtin_amdgcn_mfma_f32_16x16x32_bf16(aF[m_][0], BFA[n_][0], c_, 0, 0, 0); \
        c_ = __builtin_amdgcn_mfma_f32_16x16x32_bf16(aF[m_][1], BFA[n_][1], c_, 0, 0, 0); \
        accC[(RH) * 4 + m_][(CH) * NQN + n_] = c_;                            \
      }                                                                       \
    }                                                                         \
    __builtin_amdgcn_s_setprio(0);                                            \
  } while (0)
    for (int t2 = 0; t2 < NT; ++t2) {
      const int cur = t2 & 1, nxt = cur ^ 1;
      const int ktn  = (t2 + 1 < NT) ? t2 + 1 : NT - 1;
      const int ktn2 = (t2 + 2 < NT) ? t2 + 2 : NT - 1;

      // P1
      stageA(nxt, 0, ktn);
      stageA(nxt, 1, ktn);
      readA(cur, 0); readB(cur, 0, bF0);
      BARRIER(); WAIT_LGKM0();
      MFMAQ(0, 0, bF0);
      BARRIER();
      // P2
      readB(cur, 1, bF1);
      BARRIER(); WAIT_LGKM0();
      MFMAQ(0, 1, bF1);
      BARRIER();
      // P3
      WAIT_VM(BL + 4);
      SCHED_FENCE();
      writeBhalf(nxt, bq0, 0);
      loadBhalf(bq0, 0, ktn2);
      readA(cur, 1);
      BARRIER(); WAIT_LGKM0();
      MFMAQ(1, 1, bF1);
      BARRIER();
      // P4
      WAIT_VM(BL + 4);
      SCHED_FENCE();
      writeBhalf(nxt, bq1, 1);
      loadBhalf(bq1, 1, ktn2);
      WAIT_VM(2 * BL);
      BARRIER(); WAIT_LGKM0();
      MFMAQ(1, 0, bF0);
      BARRIER();
    }
#undef MFMAQ
  } else {
    // ---------------- merged 2-phase schedule (GEMM2, BN=128) ----------------
    // Ledger (steady {c0(2),c1(2)}): P1 +A4; vm(6)->c0; +nc0.
    //                                P2 vm(6)->c1; +nc1; vm(4)->A.
    bf16x8 bFall[NACC][2];
    auto readBall = [&](int buf) {
      const char* base = ldsB(buf) + (wc * WNC + rowLane) * 128;
#pragma unroll
      for (int n = 0; n < NACC; ++n)
#pragma unroll
        for (int ks = 0; ks < 2; ++ks) {
          int g = (ks * 4 + grpA) ^ swzm;
          bFall[n][ks] = *(const bf16x8*)(base + n * (16 * 128) + g * 16);
        }
    };
#define MFMAQ2(RH)                                                            \
  do {                                                                        \
    __builtin_amdgcn_s_setprio(1);                                            \
    _Pragma("unroll")                                                         \
    for (int m_ = 0; m_ < 4; ++m_) {                                          \
      _Pragma("unroll")                                                       \
      for (int n_ = 0; n_ < NACC; ++n_) {                                     \
        f32x4 c_ = accC[(RH) * 4 + m_][n_];                                   \
        c_ = __builtin_amdgcn_mfma_f32_16x16x32_bf16(aF[m_][0], bFall[n_][0], c_, 0, 0, 0); \
        c_ = __builtin_amdgcn_mfma_f32_16x16x32_bf16(aF[m_][1], bFall[n_][1], c_, 0, 0, 0); \
        accC[(RH) * 4 + m_][n_] = c_;                                         \
      }                                                                       \
    }                                                                         \
    __builtin_amdgcn_s_setprio(0);                                            \
  } while (0)
    for (int t2 = 0; t2 < NT; ++t2) {
      const int cur = t2 & 1, nxt = cur ^ 1;
      const int ktn  = (t2 + 1 < NT) ? t2 + 1 : NT - 1;
      const int ktn2 = (t2 + 2 < NT) ? t2 + 2 : NT - 1;

      // P1: stage A(t+1); drain c0; write+reload B half0; read A0 + all B; MFMA RH0
      stageA(nxt, 0, ktn);
      stageA(nxt, 1, ktn);
      WAIT_VM(6);
      SCHED_FENCE();
      writeBhalf(nxt, bq0, 0);
      loadBhalf(bq0, 0, ktn2);
      readA(cur, 0); readBall(cur);
      BARRIER(); WAIT_LGKM0();
      MFMAQ2(0);
      BARRIER();
      // P2: drain c1; write+reload B half1; read A1; drain A; MFMA RH1
      WAIT_VM(6);
      SCHED_FENCE();
      writeBhalf(nxt, bq1, 1);
      loadBhalf(bq1, 1, ktn2);
      readA(cur, 1);
      WAIT_VM(4);
      BARRIER(); WAIT_LGKM0();
      MFMAQ2(1);
      BARRIER();
    }
#undef MFMAQ2
  }

  // ---- drain never-consumed reloads; keep dest regs alive across the drain
  WAIT_VM(0);
  SCHED_FENCE();
#pragma unroll
  for (int j = 0; j < BL; ++j) {
    asm volatile("" :: "v"(bq0[j]), "v"(bq1[j]));
  }

  // ---- epilogue. C/D: col = lane&15, row = (lane>>4)*4 + j
  const int rB0 = wr * 128 + grpA * 4;
  const int cB0 = colBase + wc * WNC + rowLane;
#pragma unroll
  for (int m = 0; m < 8; ++m) {
#pragma unroll
    for (int n = 0; n < NACC; ++n) {
#pragma unroll
      for (int j = 0; j < 4; ++j) {
        int r = rB0 + m * 16 + j;
        if (r < rowsValid) {
          size_t idx = (size_t)(rowBase + r) * N_DIM + (cB0 + n * 16);
          float v = accC[m][n][j];
          if (RELU2) {
            float rl = v > 0.f ? v : 0.f;
            float hf = (float)(__bf16)rl;              // bf16(relu(acc))
            ((__bf16*)Cout)[idx] = (__bf16)(hf * hf);  // bf16 square
          } else {
            ((float*)Cout)[idx] = (float)(__bf16)v;    // float(bf16(acc))
          }
        }
      }
    }
  }
}

extern "C" void kernel_launch(void* const* d_in, const int* in_sizes, int n_in,
                              void* d_out, int out_size, void* d_ws, size_t ws_size,
                              hipStream_t stream) {
  const float* x   = (const float*)d_in[0];
  const int*   cnt = (const int*)d_in[1];
  const float* wu  = (const float*)d_in[2];
  const float* wd  = (const float*)d_in[3];
  float* out = (float*)d_out;
  char*  ws  = (char*)d_ws;

  unsigned short* xb   = (unsigned short*)(ws);                // 16 MiB
  unsigned short* hbuf = (unsigned short*)(ws + (16u << 20));  // 32 MiB

  cvt_f32_bf16<<<2048, 256, 0, stream>>>(x, xb, T_TOK * D_DIM / 4);

  // grid.x = max tiles: floor(T/256) + E = 40 (excess blocks exit early)
  gg8<D_DIM, H_DIM, 256, true ><<<dim3(40, H_DIM / 256), dim3(512), 0, stream>>>(
      xb, wu, cnt, (void*)hbuf);
  gg8<H_DIM, D_DIM, 128, false><<<dim3(40, D_DIM / 128), dim3(512), 0, stream>>>(
      hbuf, wd, cnt, (void*)out);
}